// Round 13
// baseline (101.530 us; speedup 1.0000x reference)
//
#include <hip/hip_runtime.h>

#define HWPIX 589824
#define Wdim 768
#define Bdim 4
#define Kdim 16
#define NBINS 2048
#define RANGE_F 16.0f
#define BIN_W (RANGE_F / NBINS)
#define INV_BIN_W (NBINS / RANGE_F)
#define EPSf 1e-6f
#define QCLIP 13.8155106f   /* -log(1e-6): q >= QCLIP  <=>  phi clamps to EPS */

#define Q4 (HWPIX / 4)      // 147456 float4 groups per channel

// k_stats geometry: 288 blocks/batch x 2 iters (8 px/thread)
#define NSB_S 288
#define NBLK_S (NSB_S * Bdim)   // 1152
#define GPI_S (NSB_S * 256)     // 73728
// k_main geometry: 576 blocks/batch x 1 iter (4 px/thread); 576*256 == Q4
#define NSB_M 576
#define NBLK_M (NSB_M * Bdim)   // 2304

// ws float offsets
#define ACC_OFF 0                      // [B][K][5]
#define LOVARR_OFF 724                 // [64]
#define HIST_OFF_F 1024                // uint hist[B*K][2][NBINS]
#define NHIST (Bdim * Kdim * 2 * NBINS)
// hist tail: [NHIST..NHIST+63] = posnh, [NHIST+64] = completion counter
#define HTAIL 80
#define SPART_OFF (HIST_OFF_F + NHIST + 128)       // float [NBLK_S][80]
#define MPART_OFF (SPART_OFF + NBLK_S * 80)        // float [NBLK_M][2]

__global__ __launch_bounds__(256, 4) void k_stats(const float* __restrict__ yp,
                                                  const int* __restrict__ yt,
                                                  float* __restrict__ ws,
                                                  unsigned* __restrict__ hist) {
    int b = blockIdx.y;
    int lane = threadIdx.x & 63;
    int wv = threadIdx.x >> 6;
    __shared__ float lpart[4][80];

    // zero hist + posnh + counter (1152*256 = 294912 threads >= NHIST+80)
    {
        int gtid = (b * NSB_S + blockIdx.x) * 256 + threadIdx.x;
        if (gtid < NHIST + HTAIL) hist[gtid] = 0u;
    }

    const float4* bp4 = (const float4*)(yp + (size_t)b * 5 * HWPIX);
    const int4* bt4 = (const int4*)(yt + (size_t)b * HWPIX);

    float acc[80];
#pragma unroll
    for (int v = 0; v < 80; ++v) acc[v] = 0.f;

#pragma unroll
    for (int p = 0; p < 2; ++p) {
        int g = p * GPI_S + blockIdx.x * 256 + threadIdx.x;
        float4 coy = bp4[g];
        float4 cox = bp4[g + Q4];
        float4 csy = bp4[g + 2 * Q4];
        float4 csx = bp4[g + 3 * Q4];
        int4 ct = bt4[g];
        int hwb = g * 4;
        float oy[4] = {coy.x, coy.y, coy.z, coy.w};
        float ox[4] = {cox.x, cox.y, cox.z, cox.w};
        float sy[4] = {csy.x, csy.y, csy.z, csy.w};
        float sx[4] = {csx.x, csx.y, csx.z, csx.w};
        int tt[4] = {ct.x, ct.y, ct.z, ct.w};
#pragma unroll
        for (int j = 0; j < 4; ++j) {
            int hw = hwb + j;
            int h = hw / Wdim;
            int w = hw - h * Wdim;
            int own = tt[j] - 1;
            float vy = (float)h + oy[j];
            float vx = (float)w + ox[j];
#pragma unroll
            for (int k = 0; k < Kdim; ++k) {
                float m = (own == k) ? 1.0f : 0.0f;
                acc[k * 5 + 0] += m;
                acc[k * 5 + 1] = fmaf(m, vy, acc[k * 5 + 1]);
                acc[k * 5 + 2] = fmaf(m, vx, acc[k * 5 + 2]);
                acc[k * 5 + 3] = fmaf(m, sy[j], acc[k * 5 + 3]);
                acc[k * 5 + 4] = fmaf(m, sx[j], acc[k * 5 + 4]);
            }
        }
    }

    // fold across half-waves: lanes 0-31 own values 0..39, lanes 32-63 own 40..79
    bool lo = (lane < 32);
#pragma unroll
    for (int v = 0; v < 40; ++v) {
        float send = lo ? acc[v + 40] : acc[v];
        float got = __shfl_xor(send, 32);
        acc[v] += lo ? got : 0.f;
        acc[v + 40] += lo ? 0.f : got;
    }
#pragma unroll
    for (int v = 0; v < 40; ++v) {
        float x = lo ? acc[v] : acc[v + 40];
#pragma unroll
        for (int o = 16; o >= 1; o >>= 1) x += __shfl_xor(x, o);
        if ((lane & 31) == 0) lpart[wv][lo ? v : v + 40] = x;
    }
    __syncthreads();
    if (threadIdx.x < 80) {
        float v = lpart[0][threadIdx.x] + lpart[1][threadIdx.x] +
                  lpart[2][threadIdx.x] + lpart[3][threadIdx.x];
        ws[SPART_OFF + (size_t)(b * NSB_S + blockIdx.x) * 80 + threadIdx.x] = v;
    }
}

// 80 blocks x 256: one wave per output (320 outputs)
__global__ void k_centers2(float* __restrict__ ws) {
    int wv = threadIdx.x >> 6;
    int lane = threadIdx.x & 63;
    int gw = blockIdx.x * 4 + wv;        // 0..319
    int b = gw / 80, idx = gw - b * 80;
    const float* sp = ws + SPART_OFF + (size_t)b * NSB_S * 80 + idx;
    float x = 0.f;
    for (int j = lane; j < NSB_S; j += 64) x += sp[(size_t)j * 80];
#pragma unroll
    for (int o = 32; o >= 1; o >>= 1) x += __shfl_xor(x, o);
    if (lane == 0) ws[ACC_OFF + b * 80 + idx] = x;
}

__global__ __launch_bounds__(256, 5) void k_main(const float* __restrict__ yp,
                                                 const int* __restrict__ yt,
                                                 float* __restrict__ ws,
                                                 unsigned* __restrict__ hist) {
    int b = blockIdx.y;
    int lane = threadIdx.x & 63;
    int wv = threadIdx.x >> 6;
    __shared__ float ck_s[32];
    __shared__ float4 msw_s[17];
    __shared__ float part[4][2];
    if (threadIdx.x < 16) {
        int k = threadIdx.x;
        const float* a = ws + ACC_OFF + (size_t)b * 80 + k * 5;
        float cnt = a[0];
        float safe = fmaxf(cnt, 1.0f);
        float inv = 1.0f / safe;
        ck_s[k * 2 + 0] = a[1] * inv;
        ck_s[k * 2 + 1] = a[2] * inv;
        float4 mw;
        mw.x = a[3] * inv;
        mw.y = a[4] * inv;
        mw.z = (cnt > 0.f) ? 0.5f / cnt : 0.f;
        mw.w = 0.f;
        msw_s[k] = mw;
    }
    if (threadIdx.x == 16) msw_s[16] = (float4){0.f, 0.f, 0.f, 0.f};
    __syncthreads();

    float cky[Kdim], ckx[Kdim];
#pragma unroll
    for (int k = 0; k < Kdim; ++k) {
        cky[k] = ck_s[k * 2];
        ckx[k] = ck_s[k * 2 + 1];
    }

    unsigned* hb = hist + (size_t)(b * Kdim) * 2 * NBINS;
    unsigned* posnh = hist + (size_t)NHIST;
    const float4* bp4 = (const float4*)(yp + (size_t)b * 5 * HWPIX);
    const int4* bt4 = (const int4*)(yt + (size_t)b * HWPIX);

    int g = blockIdx.x * 256 + threadIdx.x;   // 576*256 == Q4: one group/thread
    float4 coy = bp4[g];
    float4 cox = bp4[g + Q4];
    float4 csy = bp4[g + 2 * Q4];
    float4 csx = bp4[g + 3 * Q4];
    float4 cse = bp4[g + 4 * Q4];
    int4 ct = bt4[g];

    float varsum = 0.f, ssum = 0.f;
    int hwb = g * 4;
    float oy[4] = {coy.x, coy.y, coy.z, coy.w};
    float ox[4] = {cox.x, cox.y, cox.z, cox.w};
    float sya[4] = {csy.x, csy.y, csy.z, csy.w};
    float sxa[4] = {csx.x, csx.y, csx.z, csx.w};
    float sea[4] = {cse.x, cse.y, cse.z, cse.w};
    int tt[4] = {ct.x, ct.y, ct.z, ct.w};
#pragma unroll
    for (int j = 0; j < 4; ++j) {
        int hw = hwb + j;
        int h = hw / Wdim;
        int w = hw - h * Wdim;
        int own = tt[j] - 1;
        float sy = sya[j], sx = sxa[j];
        float ey = (float)h + oy[j], ex = (float)w + ox[j];
        float sby = fmaxf(sy, EPSf), sbx = fmaxf(sx, EPSf);
        float iy = 0.5f / (sby * sby), ix = 0.5f / (sbx * sbx);

        unsigned sm = 0;
#pragma unroll
        for (int k = 0; k < Kdim; ++k) {
            float dy = ey - cky[k];
            float dx = ex - ckx[k];
            float q = fmaf(dy * dy, iy, dx * dx * ix);
            if (q < QCLIP) sm |= (1u << k);
        }
        int ow = (own >= 0) ? own : 16;
        float4 mw = msw_s[ow];
        float devv = fabsf(sy - mw.x) + fabsf(sx - mw.y);
        varsum = fmaf(devv, mw.z, varsum);

        float st = (own >= 0) ? EPSf : 0.f;
        while (sm) {  // rare slow path: near some center
            int k = __ffs(sm) - 1;
            sm &= sm - 1;
            float dy = ey - ck_s[k * 2];
            float dx = ex - ck_s[k * 2 + 1];
            float q = fmaf(dy * dy, iy, dx * dx * ix);
            float phi = expf(-q);
            phi = fminf(fmaxf(phi, EPSf), 1.0f - EPSf);
            float lg = logf(phi) - log1pf(-phi);
            bool isPos = (k == own);
            float e;
            if (isPos) {
                st = phi;
                atomicAdd(&posnh[b * Kdim + k], 1u);
                e = 1.0f - lg;
            } else {
                e = 1.0f + lg;
            }
            if (e > 0.f) {
                int bin = (int)(e * INV_BIN_W);
                if (bin > NBINS - 1) bin = NBINS - 1;
                atomicAdd(&hb[(k * 2 + (isPos ? 1 : 0)) * NBINS + bin], 1u);
            }
        }
        float dd = sea[j] - st;
        ssum = fmaf(dd, dd, ssum);
    }

#pragma unroll
    for (int o = 32; o >= 1; o >>= 1) {
        varsum += __shfl_xor(varsum, o);
        ssum += __shfl_xor(ssum, o);
    }
    if (lane == 0) {
        part[wv][0] = varsum;
        part[wv][1] = ssum;
    }
    __syncthreads();
    if (threadIdx.x < 2) {
        float v = part[0][threadIdx.x] + part[1][threadIdx.x] +
                  part[2][threadIdx.x] + part[3][threadIdx.x];
        ws[MPART_OFF + (size_t)(b * NSB_M + blockIdx.x) * 2 + threadIdx.x] = v;
    }
}

// One wave per (b,k): suffix-scan histogram top-down, trapezoid-integrate.
// Last block to finish also does the final combine (counter in hist[NHIST+64]).
__global__ void k_lovasz(float* __restrict__ ws, unsigned* __restrict__ hist,
                         float* __restrict__ out) {
    int i = blockIdx.x;  // 0..63
    int lane = threadIdx.x;
    float P = ws[ACC_OFF + i * 5];
    float res = 0.f;
    if (P >= 0.5f) {
        const unsigned* hn = hist + (size_t)i * 2 * NBINS;
        const unsigned* hp = hn + NBINS;
        const unsigned* posnh = hist + (size_t)NHIST;
        const float C_LO = logf(EPSf) - log1pf(-EPSf);
        const int HOTBIN = (int)((1.0f - C_LO) * INV_BIN_W);
        int deficit = (int)(P + 0.5f) - (int)posnh[i];
        int carry_p = 0, carry_n = 0;
        float Jtop = 0.f;
        float trap = 0.f;
        for (int c = NBINS / 64 - 1; c >= 0; --c) {
            int m = c * 64 + lane;
            int vp = (int)hp[m];
            int vn = (int)hn[m];
            if (m == HOTBIN) vp += deficit;
            for (int o = 1; o < 64; o <<= 1) {
                int tp = __shfl_down(vp, o);
                int tn = __shfl_down(vn, o);
                if (lane + o < 64) { vp += tp; vn += tn; }
            }
            float p_edge = (float)(carry_p + vp);
            float n_edge = (float)(carry_n + vn);
            float J = 1.0f - (P - p_edge) / (P + n_edge);
            float Jn = __shfl_down(J, 1);
            if (lane == 63) Jn = Jtop;
            trap += 0.5f * (J + Jn);
            carry_p += __shfl(vp, 0);
            carry_n += __shfl(vn, 0);
            Jtop = __shfl(J, 0);
        }
        for (int o = 1; o < 64; o <<= 1) {
            float t2 = __shfl_down(trap, o);
            if (lane + o < 64) trap += t2;
        }
        res = trap * BIN_W;
    }
    if (lane == 0) ws[LOVARR_OFF + i] = res;
    __threadfence();

    __shared__ unsigned ticket;
    if (lane == 0) ticket = atomicAdd(&hist[NHIST + 64], 1u);
    __syncthreads();
    if (ticket != 63u) return;

    float v = 0.f, s = 0.f, l = 0.f, pr = 0.f;
    for (int j = lane; j < NBLK_M; j += 64) {
        v += ws[MPART_OFF + 2 * j];
        s += ws[MPART_OFF + 2 * j + 1];
    }
    l = ws[LOVARR_OFF + lane];
    pr = (ws[ACC_OFF + lane * 5] > 0.f) ? 1.f : 0.f;
#pragma unroll
    for (int o = 32; o >= 1; o >>= 1) {
        v += __shfl_xor(v, o);
        s += __shfl_xor(s, o);
        l += __shfl_xor(l, o);
        pr += __shfl_xor(pr, o);
    }
    if (lane == 0) {
        float npres = fmaxf(pr, 1.0f);
        out[0] = l / npres + 10.0f * (v / npres) +
                 s / (float)((size_t)Bdim * HWPIX);
    }
}

extern "C" void kernel_launch(void* const* d_in, const int* in_sizes, int n_in,
                              void* d_out, int out_size, void* d_ws, size_t ws_size,
                              hipStream_t stream) {
    const float* yp = (const float*)d_in[0];
    const int* yt = (const int*)d_in[1];
    float* ws = (float*)d_ws;
    unsigned* hist = (unsigned*)((char*)d_ws + HIST_OFF_F * 4);

    dim3 gs(NSB_S, Bdim);
    dim3 gm(NSB_M, Bdim);
    k_stats<<<gs, 256, 0, stream>>>(yp, yt, ws, hist);
    k_centers2<<<80, 256, 0, stream>>>(ws);
    k_main<<<gm, 256, 0, stream>>>(yp, yt, ws, hist);
    k_lovasz<<<64, 64, 0, stream>>>(ws, hist, (float*)d_out);
}

// Round 14
// 91.925 us; speedup vs baseline: 1.1045x; 1.1045x over previous
//
#include <hip/hip_runtime.h>
#include <stdint.h>

#define HWPIX 589824
#define Wdim 768
#define Bdim 4
#define Kdim 16
#define NBINS 2048
#define RANGE_F 16.0f
#define BIN_W (RANGE_F / NBINS)
#define INV_BIN_W (NBINS / RANGE_F)
#define EPSf 1e-6f
#define QCLIP 13.8155106f   /* -log(1e-6): q >= QCLIP  <=>  phi clamps to EPS */

#define Q4 (HWPIX / 4)      // 147456 float4 groups per channel
#define NSB 192             // blocks per batch
#define NBLK (NSB * Bdim)   // 768 blocks
#define GPI (NSB * 256)     // float4-groups per tile per batch (3 tiles)

// ws float offsets
#define ACC_OFF 0                      // [B][K][5]
#define LOVARR_OFF 724                 // [64]
#define HIST_OFF_F 1024                // uint hist[B*K][2][NBINS]
#define NHIST (Bdim * Kdim * 2 * NBINS)
// hist tail: [NHIST..NHIST+63] = posnh, [NHIST+64] = completion counter
#define HTAIL 80
#define SPART_OFF (HIST_OFF_F + NHIST + 128)       // float [NBLK][80]
#define MPART_OFF (SPART_OFF + NBLK * 80)          // float [NBLK][2]

typedef const __attribute__((address_space(1))) void gas_void;
typedef __attribute__((address_space(3))) void las_void;

__device__ __forceinline__ void load_lds16(const void* gsrc, void* ldst) {
    __builtin_amdgcn_global_load_lds((gas_void*)gsrc, (las_void*)ldst, 16, 0, 0);
}

__device__ __forceinline__ void wait_and_barrier() {
    asm volatile("s_waitcnt vmcnt(0)" ::: "memory");
    __builtin_amdgcn_s_barrier();
    __builtin_amdgcn_sched_barrier(0);
}

__global__ __launch_bounds__(256, 3) void k_stats(const float* __restrict__ yp,
                                                  const int* __restrict__ yt,
                                                  float* __restrict__ ws,
                                                  unsigned* __restrict__ hist) {
    int b = blockIdx.y;
    int tid = threadIdx.x;
    int lane = tid & 63;
    int wv = tid >> 6;
    __shared__ float4 stage[2][5][256];   // ch: oy,ox,sy,sx,yt(bits) — 40 KB
    __shared__ float lpart[4][80];

    // zero hist + posnh + counter (folded memset)
    {
        int gtid = (b * NSB + blockIdx.x) * 256 + tid;
        for (int i = gtid; i < NHIST + HTAIL; i += NBLK * 256) hist[i] = 0u;
    }

    const float4* bp4 = (const float4*)(yp + (size_t)b * 5 * HWPIX);
    const int4* bt4 = (const int4*)(yt + (size_t)b * HWPIX);

    float acc[80];
#pragma unroll
    for (int v = 0; v < 80; ++v) acc[v] = 0.f;

    int base0 = blockIdx.x * 256;
    // prologue: stage tile 0 into buf 0
    {
        int gl = base0 + tid;
        int ldb = wv << 6;
        load_lds16(&bp4[gl],          &stage[0][0][ldb]);
        load_lds16(&bp4[gl + Q4],     &stage[0][1][ldb]);
        load_lds16(&bp4[gl + 2 * Q4], &stage[0][2][ldb]);
        load_lds16(&bp4[gl + 3 * Q4], &stage[0][3][ldb]);
        load_lds16(&bt4[gl],          &stage[0][4][ldb]);
    }
    wait_and_barrier();

    int cur = 0;
#pragma unroll
    for (int p = 0; p < 3; ++p) {
        if (p < 2) {  // stage next tile into other buffer (flies during compute)
            int gl = (p + 1) * GPI + base0 + tid;
            int ldb = wv << 6;
            int nb = cur ^ 1;
            load_lds16(&bp4[gl],          &stage[nb][0][ldb]);
            load_lds16(&bp4[gl + Q4],     &stage[nb][1][ldb]);
            load_lds16(&bp4[gl + 2 * Q4], &stage[nb][2][ldb]);
            load_lds16(&bp4[gl + 3 * Q4], &stage[nb][3][ldb]);
            load_lds16(&bt4[gl],          &stage[nb][4][ldb]);
        }
        // compute current tile from LDS
        {
            float4 coy = stage[cur][0][tid];
            float4 cox = stage[cur][1][tid];
            float4 csy = stage[cur][2][tid];
            float4 csx = stage[cur][3][tid];
            int4 ct = ((const int4*)&stage[cur][4][0])[tid];
            int g = p * GPI + base0 + tid;
            int hwb = g * 4;
            float oy[4] = {coy.x, coy.y, coy.z, coy.w};
            float ox[4] = {cox.x, cox.y, cox.z, cox.w};
            float sy[4] = {csy.x, csy.y, csy.z, csy.w};
            float sx[4] = {csx.x, csx.y, csx.z, csx.w};
            int tt[4] = {ct.x, ct.y, ct.z, ct.w};
#pragma unroll
            for (int j = 0; j < 4; ++j) {
                int hw = hwb + j;
                int h = hw / Wdim;
                int w = hw - h * Wdim;
                int own = tt[j] - 1;
                float vy = (float)h + oy[j];
                float vx = (float)w + ox[j];
#pragma unroll
                for (int k = 0; k < Kdim; ++k) {
                    float m = (own == k) ? 1.0f : 0.0f;
                    acc[k * 5 + 0] += m;
                    acc[k * 5 + 1] = fmaf(m, vy, acc[k * 5 + 1]);
                    acc[k * 5 + 2] = fmaf(m, vx, acc[k * 5 + 2]);
                    acc[k * 5 + 3] = fmaf(m, sy[j], acc[k * 5 + 3]);
                    acc[k * 5 + 4] = fmaf(m, sx[j], acc[k * 5 + 4]);
                }
            }
        }
        wait_and_barrier();   // next buf staged; all waves done reading cur
        cur ^= 1;
    }

    // fold across half-waves: lanes 0-31 own values 0..39, lanes 32-63 own 40..79
    bool lo = (lane < 32);
#pragma unroll
    for (int v = 0; v < 40; ++v) {
        float send = lo ? acc[v + 40] : acc[v];
        float got = __shfl_xor(send, 32);
        acc[v] += lo ? got : 0.f;
        acc[v + 40] += lo ? 0.f : got;
    }
#pragma unroll
    for (int v = 0; v < 40; ++v) {
        float x = lo ? acc[v] : acc[v + 40];
#pragma unroll
        for (int o = 16; o >= 1; o >>= 1) x += __shfl_xor(x, o);
        if ((lane & 31) == 0) lpart[wv][lo ? v : v + 40] = x;
    }
    __syncthreads();
    if (tid < 80) {
        float v = lpart[0][tid] + lpart[1][tid] + lpart[2][tid] + lpart[3][tid];
        ws[SPART_OFF + (size_t)(b * NSB + blockIdx.x) * 80 + tid] = v;
    }
}

// 80 blocks x 256: one wave per output (320 outputs)
__global__ void k_centers2(float* __restrict__ ws) {
    int wv = threadIdx.x >> 6;
    int lane = threadIdx.x & 63;
    int gw = blockIdx.x * 4 + wv;        // 0..319
    int b = gw / 80, idx = gw - b * 80;
    const float* sp = ws + SPART_OFF + (size_t)b * NSB * 80 + idx;
    float x = sp[(size_t)lane * 80] + sp[(size_t)(lane + 64) * 80] +
              sp[(size_t)(lane + 128) * 80];
#pragma unroll
    for (int o = 32; o >= 1; o >>= 1) x += __shfl_xor(x, o);
    if (lane == 0) ws[ACC_OFF + b * 80 + idx] = x;
}

__global__ __launch_bounds__(256, 3) void k_main(const float* __restrict__ yp,
                                                 const int* __restrict__ yt,
                                                 float* __restrict__ ws,
                                                 unsigned* __restrict__ hist) {
    int b = blockIdx.y;
    int tid = threadIdx.x;
    int lane = tid & 63;
    int wv = tid >> 6;
    __shared__ float4 stage[2][6][256];   // oy,ox,sy,sx,se,yt — 48 KB
    __shared__ float ck_s[32];
    __shared__ float4 msw_s[17];
    __shared__ float part[4][2];

    const float4* bp4 = (const float4*)(yp + (size_t)b * 5 * HWPIX);
    const int4* bt4 = (const int4*)(yt + (size_t)b * HWPIX);
    int base0 = blockIdx.x * 256;

    // stage tile 0 while doing the prologue
    {
        int gl = base0 + tid;
        int ldb = wv << 6;
        load_lds16(&bp4[gl],          &stage[0][0][ldb]);
        load_lds16(&bp4[gl + Q4],     &stage[0][1][ldb]);
        load_lds16(&bp4[gl + 2 * Q4], &stage[0][2][ldb]);
        load_lds16(&bp4[gl + 3 * Q4], &stage[0][3][ldb]);
        load_lds16(&bp4[gl + 4 * Q4], &stage[0][4][ldb]);
        load_lds16(&bt4[gl],          &stage[0][5][ldb]);
    }
    if (tid < 16) {
        int k = tid;
        const float* a = ws + ACC_OFF + (size_t)b * 80 + k * 5;
        float cnt = a[0];
        float safe = fmaxf(cnt, 1.0f);
        float inv = 1.0f / safe;
        ck_s[k * 2 + 0] = a[1] * inv;
        ck_s[k * 2 + 1] = a[2] * inv;
        float4 mw;
        mw.x = a[3] * inv;
        mw.y = a[4] * inv;
        mw.z = (cnt > 0.f) ? 0.5f / cnt : 0.f;
        mw.w = 0.f;
        msw_s[k] = mw;
    }
    if (tid == 16) msw_s[16] = (float4){0.f, 0.f, 0.f, 0.f};
    wait_and_barrier();

    float cky[Kdim], ckx[Kdim];
#pragma unroll
    for (int k = 0; k < Kdim; ++k) {
        cky[k] = ck_s[k * 2];
        ckx[k] = ck_s[k * 2 + 1];
    }

    unsigned* hb = hist + (size_t)(b * Kdim) * 2 * NBINS;
    unsigned* posnh = hist + (size_t)NHIST;

    float varsum = 0.f, ssum = 0.f;
    int cur = 0;
#pragma unroll
    for (int p = 0; p < 3; ++p) {
        if (p < 2) {
            int gl = (p + 1) * GPI + base0 + tid;
            int ldb = wv << 6;
            int nb = cur ^ 1;
            load_lds16(&bp4[gl],          &stage[nb][0][ldb]);
            load_lds16(&bp4[gl + Q4],     &stage[nb][1][ldb]);
            load_lds16(&bp4[gl + 2 * Q4], &stage[nb][2][ldb]);
            load_lds16(&bp4[gl + 3 * Q4], &stage[nb][3][ldb]);
            load_lds16(&bp4[gl + 4 * Q4], &stage[nb][4][ldb]);
            load_lds16(&bt4[gl],          &stage[nb][5][ldb]);
        }
        {
            float4 coy = stage[cur][0][tid];
            float4 cox = stage[cur][1][tid];
            float4 csy = stage[cur][2][tid];
            float4 csx = stage[cur][3][tid];
            float4 cse = stage[cur][4][tid];
            int4 ct = ((const int4*)&stage[cur][5][0])[tid];
            int g = p * GPI + base0 + tid;
            int hwb = g * 4;
            float oy[4] = {coy.x, coy.y, coy.z, coy.w};
            float ox[4] = {cox.x, cox.y, cox.z, cox.w};
            float sya[4] = {csy.x, csy.y, csy.z, csy.w};
            float sxa[4] = {csx.x, csx.y, csx.z, csx.w};
            float sea[4] = {cse.x, cse.y, cse.z, cse.w};
            int tt[4] = {ct.x, ct.y, ct.z, ct.w};
#pragma unroll
            for (int j = 0; j < 4; ++j) {
                int hw = hwb + j;
                int h = hw / Wdim;
                int w = hw - h * Wdim;
                int own = tt[j] - 1;
                float sy = sya[j], sx = sxa[j];
                float ey = (float)h + oy[j], ex = (float)w + ox[j];
                float sby = fmaxf(sy, EPSf), sbx = fmaxf(sx, EPSf);
                float iy = 0.5f / (sby * sby), ix = 0.5f / (sbx * sbx);

                unsigned sm = 0;
#pragma unroll
                for (int k = 0; k < Kdim; ++k) {
                    float dy = ey - cky[k];
                    float dx = ex - ckx[k];
                    float q = fmaf(dy * dy, iy, dx * dx * ix);
                    if (q < QCLIP) sm |= (1u << k);
                }
                int ow = (own >= 0) ? own : 16;
                float4 mw = msw_s[ow];
                float devv = fabsf(sy - mw.x) + fabsf(sx - mw.y);
                varsum = fmaf(devv, mw.z, varsum);

                float st = (own >= 0) ? EPSf : 0.f;
                while (sm) {  // rare slow path: near some center
                    int k = __ffs(sm) - 1;
                    sm &= sm - 1;
                    float dy = ey - ck_s[k * 2];
                    float dx = ex - ck_s[k * 2 + 1];
                    float q = fmaf(dy * dy, iy, dx * dx * ix);
                    float phi = expf(-q);
                    phi = fminf(fmaxf(phi, EPSf), 1.0f - EPSf);
                    float lg = logf(phi) - log1pf(-phi);
                    bool isPos = (k == own);
                    float e;
                    if (isPos) {
                        st = phi;
                        atomicAdd(&posnh[b * Kdim + k], 1u);
                        e = 1.0f - lg;
                    } else {
                        e = 1.0f + lg;
                    }
                    if (e > 0.f) {
                        int bin = (int)(e * INV_BIN_W);
                        if (bin > NBINS - 1) bin = NBINS - 1;
                        atomicAdd(&hb[(k * 2 + (isPos ? 1 : 0)) * NBINS + bin], 1u);
                    }
                }
                float dd = sea[j] - st;
                ssum = fmaf(dd, dd, ssum);
            }
        }
        wait_and_barrier();
        cur ^= 1;
    }

#pragma unroll
    for (int o = 32; o >= 1; o >>= 1) {
        varsum += __shfl_xor(varsum, o);
        ssum += __shfl_xor(ssum, o);
    }
    if (lane == 0) {
        part[wv][0] = varsum;
        part[wv][1] = ssum;
    }
    __syncthreads();
    if (tid < 2) {
        float v = part[0][tid] + part[1][tid] + part[2][tid] + part[3][tid];
        ws[MPART_OFF + (size_t)(b * NSB + blockIdx.x) * 2 + tid] = v;
    }
}

// One wave per (b,k): suffix-scan histogram top-down, trapezoid-integrate.
// Last block to finish also does the final combine (counter in hist[NHIST+64]).
__global__ void k_lovasz(float* __restrict__ ws, unsigned* __restrict__ hist,
                         float* __restrict__ out) {
    int i = blockIdx.x;  // 0..63
    int lane = threadIdx.x;
    float P = ws[ACC_OFF + i * 5];
    float res = 0.f;
    if (P >= 0.5f) {
        const unsigned* hn = hist + (size_t)i * 2 * NBINS;
        const unsigned* hp = hn + NBINS;
        const unsigned* posnh = hist + (size_t)NHIST;
        const float C_LO = logf(EPSf) - log1pf(-EPSf);
        const int HOTBIN = (int)((1.0f - C_LO) * INV_BIN_W);
        int deficit = (int)(P + 0.5f) - (int)posnh[i];
        int carry_p = 0, carry_n = 0;
        float Jtop = 0.f;
        float trap = 0.f;
        for (int c = NBINS / 64 - 1; c >= 0; --c) {
            int m = c * 64 + lane;
            int vp = (int)hp[m];
            int vn = (int)hn[m];
            if (m == HOTBIN) vp += deficit;
            for (int o = 1; o < 64; o <<= 1) {
                int tp = __shfl_down(vp, o);
                int tn = __shfl_down(vn, o);
                if (lane + o < 64) { vp += tp; vn += tn; }
            }
            float p_edge = (float)(carry_p + vp);
            float n_edge = (float)(carry_n + vn);
            float J = 1.0f - (P - p_edge) / (P + n_edge);
            float Jn = __shfl_down(J, 1);
            if (lane == 63) Jn = Jtop;
            trap += 0.5f * (J + Jn);
            carry_p += __shfl(vp, 0);
            carry_n += __shfl(vn, 0);
            Jtop = __shfl(J, 0);
        }
        for (int o = 1; o < 64; o <<= 1) {
            float t2 = __shfl_down(trap, o);
            if (lane + o < 64) trap += t2;
        }
        res = trap * BIN_W;
    }
    if (lane == 0) ws[LOVARR_OFF + i] = res;
    __threadfence();

    __shared__ unsigned ticket;
    if (lane == 0) ticket = atomicAdd(&hist[NHIST + 64], 1u);
    __syncthreads();
    if (ticket != 63u) return;

    float v = 0.f, s = 0.f, l = 0.f, pr = 0.f;
    for (int j = lane; j < NBLK; j += 64) {
        v += ws[MPART_OFF + 2 * j];
        s += ws[MPART_OFF + 2 * j + 1];
    }
    l = ws[LOVARR_OFF + lane];
    pr = (ws[ACC_OFF + lane * 5] > 0.f) ? 1.f : 0.f;
#pragma unroll
    for (int o = 32; o >= 1; o >>= 1) {
        v += __shfl_xor(v, o);
        s += __shfl_xor(s, o);
        l += __shfl_xor(l, o);
        pr += __shfl_xor(pr, o);
    }
    if (lane == 0) {
        float npres = fmaxf(pr, 1.0f);
        out[0] = l / npres + 10.0f * (v / npres) +
                 s / (float)((size_t)Bdim * HWPIX);
    }
}

extern "C" void kernel_launch(void* const* d_in, const int* in_sizes, int n_in,
                              void* d_out, int out_size, void* d_ws, size_t ws_size,
                              hipStream_t stream) {
    const float* yp = (const float*)d_in[0];
    const int* yt = (const int*)d_in[1];
    float* ws = (float*)d_ws;
    unsigned* hist = (unsigned*)((char*)d_ws + HIST_OFF_F * 4);

    dim3 g(NSB, Bdim);
    k_stats<<<g, 256, 0, stream>>>(yp, yt, ws, hist);
    k_centers2<<<80, 256, 0, stream>>>(ws);
    k_main<<<g, 256, 0, stream>>>(yp, yt, ws, hist);
    k_lovasz<<<64, 64, 0, stream>>>(ws, hist, (float*)d_out);
}